// Round 12
// baseline (586.661 us; speedup 1.0000x reference)
//
#include <hip/hip_runtime.h>
#include <hip/hip_bf16.h>

#define E_     8
#define C_     1024
#define H_     4096
#define N_TOK  4096
#define TOPK   2
#define NSLOT  (N_TOK*TOPK)   // 8192
#define SPAD   (NSLOT+256)    // padded rows for 256-row tile-tail reads

#define LPAD 40               // slow-path LDS row stride

typedef __attribute__((ext_vector_type(4))) float f32x4;
typedef __attribute__((ext_vector_type(8))) short short8;

__device__ __forceinline__ unsigned short f2bf(float f) {
    return __builtin_bit_cast(unsigned short, __float2bfloat16(f));
}

__device__ __forceinline__ void gload16(const void* g, const void* l) {
    __builtin_amdgcn_global_load_lds(
        (const __attribute__((address_space(1))) unsigned int*)g,
        (__attribute__((address_space(3))) unsigned int*)l, 16, 0, 0);
}

#define WAITVM_(n) asm volatile("s_waitcnt vmcnt(" #n ")" ::: "memory")
#define WAITVM(n) WAITVM_(n)

// ---------------- router ----------------
__global__ void router_kernel(const float* __restrict__ x, const float* __restrict__ Wg,
                              int* __restrict__ sel, float* __restrict__ wts) {
    int wave = (blockIdx.x * blockDim.x + threadIdx.x) >> 6;
    int lane = threadIdx.x & 63;
    if (wave >= N_TOK) return;
    const float* xr = x + (size_t)wave * C_;
    float acc[E_];
#pragma unroll
    for (int e = 0; e < E_; ++e) acc[e] = 0.f;
    for (int c = lane; c < C_; c += 64) {
        float xv = xr[c];
#pragma unroll
        for (int e = 0; e < E_; ++e) acc[e] += xv * Wg[e * C_ + c];
    }
#pragma unroll
    for (int e = 0; e < E_; ++e) {
#pragma unroll
        for (int off = 32; off > 0; off >>= 1) acc[e] += __shfl_xor(acc[e], off);
    }
    if (lane == 0) {
        float mx = acc[0];
#pragma unroll
        for (int e = 1; e < E_; ++e) mx = fmaxf(mx, acc[e]);
        float p[E_]; float s = 0.f;
#pragma unroll
        for (int e = 0; e < E_; ++e) { p[e] = __expf(acc[e] - mx); s += p[e]; }
        float inv = 1.f / s;
#pragma unroll
        for (int e = 0; e < E_; ++e) p[e] *= inv;
        int b0 = 0; float v0 = p[0];
#pragma unroll
        for (int e = 1; e < E_; ++e) if (p[e] > v0) { v0 = p[e]; b0 = e; }
        int b1 = -1; float v1 = -1.f;
#pragma unroll
        for (int e = 0; e < E_; ++e) { if (e != b0 && p[e] > v1) { v1 = p[e]; b1 = e; } }
        float isum = 1.f / (v0 + v1);
        sel[wave*2]   = b0; sel[wave*2+1] = b1;
        wts[wave*2]   = v0 * isum; wts[wave*2+1] = v1 * isum;
    }
}

// ---------------- assign ----------------
__global__ void assign_kernel(const int* __restrict__ sel, const float* __restrict__ wts,
                              int* __restrict__ counts, int* __restrict__ offsets,
                              int* __restrict__ pos_of_slot, int* __restrict__ token_of,
                              float* __restrict__ slotw) {
    __shared__ int cnt[256][E_];
    __shared__ int offs[E_];
    int t = threadIdx.x;
    const int PER = NSLOT / 256;   // 32
    int base = t * PER;
    int loc[E_];
#pragma unroll
    for (int e = 0; e < E_; ++e) loc[e] = 0;
    for (int i = 0; i < PER; ++i) loc[sel[base + i]]++;
#pragma unroll
    for (int e = 0; e < E_; ++e) cnt[t][e] = loc[e];
    __syncthreads();
    if (t < E_) {
        int run = 0;
        for (int i = 0; i < 256; ++i) { int c = cnt[i][t]; cnt[i][t] = run; run += c; }
        counts[t] = run;
    }
    __syncthreads();
    if (t == 0) {
        int s = 0;
        for (int e = 0; e < E_; ++e) { offs[e] = s; offsets[e] = s; s += counts[e]; }
    }
    __syncthreads();
    int run[E_];
#pragma unroll
    for (int e = 0; e < E_; ++e) run[e] = offs[e] + cnt[t][e];
    for (int i = 0; i < PER; ++i) {
        int s = base + i;
        int e = sel[s];
        int p = run[e]++;
        pos_of_slot[s] = p;
        token_of[p] = s >> 1;
        slotw[p] = wts[s];
    }
}

// ---------------- copy ----------------
__global__ void copy_kernel(const float* __restrict__ x, const int* __restrict__ pos_of_slot,
                            unsigned short* __restrict__ Xg) {
    int slot = blockIdx.x * 4 + (threadIdx.x >> 6);
    int lane = threadIdx.x & 63;
    int pos = pos_of_slot[slot];
    int n = slot >> 1;
    const float* xr = x + (size_t)n * C_;
    unsigned short* dst = Xg + (size_t)pos * C_;
#pragma unroll
    for (int i = 0; i < 4; ++i) {
        int c0 = i * 256 + lane * 4;
        float4 v = *(const float4*)(xr + c0);
        ushort4 b;
        b.x = f2bf(v.x); b.y = f2bf(v.y); b.z = f2bf(v.z); b.w = f2bf(v.w);
        *(ushort4*)(dst + c0) = b;
    }
}

// ---------------- wconv: fp32 [R][Cc] -> bf16 [Cc][R] (used for W2) ----------------
__global__ void wconv_kernel(const float* __restrict__ src, unsigned short* __restrict__ dst,
                             int R, int Cc) {
    int e = blockIdx.z;
    int c0 = blockIdx.x * 64;
    int r0 = blockIdx.y * 64;
    const float* s = src + (size_t)e * R * Cc;
    unsigned short* d = dst + (size_t)e * R * Cc;
    __shared__ unsigned short t_[64][72];
    int t = threadIdx.x;
    int tr = t >> 4, tc4 = (t & 15) * 4;
#pragma unroll
    for (int i = 0; i < 4; ++i) {
        int r = tr + i * 16;
        float4 v = *(const float4*)(s + (size_t)(r0 + r) * Cc + c0 + tc4);
        t_[r][tc4+0] = f2bf(v.x); t_[r][tc4+1] = f2bf(v.y);
        t_[r][tc4+2] = f2bf(v.z); t_[r][tc4+3] = f2bf(v.w);
    }
    __syncthreads();
    int oc = t >> 2, seg = (t & 3) * 16;
    short8 w0, w1;
#pragma unroll
    for (int j = 0; j < 8; ++j) {
        w0[j] = (short)t_[seg + j][oc];
        w1[j] = (short)t_[seg + 8 + j][oc];
    }
    unsigned short* dp = d + (size_t)(c0 + oc) * R + r0 + seg;
    *(short8*)dp = w0;
    *(short8*)(dp + 8) = w1;
}

// ---------------- wconv13: W1/W3 [E][C][H] fp32 -> interleaved W13t bf16 ----------------
// W13t[e] is [8192][1024]: row nI = (h>>4)*32 + (h&15) + is3*16, col = c.
// 16-col h-groups alternate W1 / W3 so silu pairing is lane-local in gemm1.
__global__ void wconv13_kernel(const float* __restrict__ src, unsigned short* __restrict__ dst,
                               int is3) {
    int e = blockIdx.z;
    int c0 = blockIdx.x * 64;   // h dim
    int r0 = blockIdx.y * 64;   // c dim
    const float* s = src + (size_t)e * C_ * H_;
    unsigned short* d = dst + (size_t)e * 8192 * C_;
    __shared__ unsigned short t_[64][72];
    int t = threadIdx.x;
    int tr = t >> 4, tc4 = (t & 15) * 4;
#pragma unroll
    for (int i = 0; i < 4; ++i) {
        int r = tr + i * 16;
        float4 v = *(const float4*)(s + (size_t)(r0 + r) * H_ + c0 + tc4);
        t_[r][tc4+0] = f2bf(v.x); t_[r][tc4+1] = f2bf(v.y);
        t_[r][tc4+2] = f2bf(v.z); t_[r][tc4+3] = f2bf(v.w);
    }
    __syncthreads();
    int oc = t >> 2, seg = (t & 3) * 16;
    short8 w0, w1;
#pragma unroll
    for (int j = 0; j < 8; ++j) {
        w0[j] = (short)t_[seg + j][oc];
        w1[j] = (short)t_[seg + 8 + j][oc];
    }
    int h = c0 + oc;
    int nI = ((h >> 4) << 5) + (h & 15) + is3 * 16;
    unsigned short* dp = d + (size_t)nI * C_ + r0 + seg;
    *(short8*)dp = w0;
    *(short8*)(dp + 8) = w1;
}

// ============ 256x256-tile GEMMs: r4's proven phase skeleton, 2x MFMA density ============
// 8 waves (2M x 4N), per-wave out 128x64, acc[8][4]. BK=64. LDS 128KB: 2 dbuf x
// (A 256x64 + B 256x64), each tile as 2 halves of 16 x 1024B blocks (block = 8 rows x
// 8 chunks of 16B, chunk-major; staged lane->(r=lane&7,c=lane>>3); conflict-free reads).
// Per K-tile 4 phases: {barrier; stage 1 half (2 gloads) into dbuf^1; WAITVM(2/4/6/8);
// barrier; sched_barrier; ds_read frags; setprio; 16 MFMA; setprio}.
// Ledger: prologue 8 loads (tile 0); F0's WAITVM(2) retires exactly tile-t's 8 (staged
// one K-tile earlier). Dummy tail re-stage keeps it issue-invariant; WAITVM(0) at end.

#define LDSOFF(lr, kc) ((((lr) >> 3) << 10) + ((kc) << 7) + (((lr) & 7) << 4))

__global__ __launch_bounds__(512, 2) void gemm1_256(
        const unsigned short* __restrict__ Xg, const unsigned short* __restrict__ W13t,
        unsigned short* __restrict__ G,
        const int* __restrict__ counts, const int* __restrict__ offsets) {
    int ct = blockIdx.x;            // 32 col tiles of 256 interleaved cols = 128 h
    int rslot = blockIdx.y;         // e*32 + rt
    int e = rslot >> 5, rt = rslot & 31;
    int ne = counts[e];
    if (rt * 256 >= ne) return;
    int row0 = offsets[e] + rt * 256;

    extern __shared__ char lds[];   // [2][A 32KB][B 32KB]

    int tid = threadIdx.x, lane = tid & 63, wid = tid >> 6;
    int wm = wid >> 2, wn = wid & 3;           // 2M x 4N
    int fr = lane & 15, q = lane >> 4;
    int sr = lane & 7, sc = lane >> 3;         // staging lane map

    const unsigned short* Ap = Xg + (size_t)row0 * C_;
    const unsigned short* Bp = W13t + ((size_t)e * 8192 + ct * 256) * C_;

    f32x4 acc[8][4];
#pragma unroll
    for (int m = 0; m < 8; ++m)
#pragma unroll
        for (int n = 0; n < 4; ++n) acc[m][n] = (f32x4){0.f,0.f,0.f,0.f};

    auto STAGE_A = [&](int ts, int half, int dd) {   // 2 gloads/wave
        int k0 = ts * 64;
#pragma unroll
        for (int j = 0; j < 2; ++j) {
            int g = wid * 2 + j;                      // block 0..15 within half
            int row = half * 128 + g * 8 + sr;
            gload16(Ap + (size_t)row * C_ + k0 + sc * 8,
                    lds + dd * 65536 + half * 16384 + g * 1024);
        }
    };
    auto STAGE_B = [&](int ts, int half, int dd) {
        int k0 = ts * 64;
#pragma unroll
        for (int j = 0; j < 2; ++j) {
            int g = wid * 2 + j;
            int row = half * 128 + g * 8 + sr;
            gload16(Bp + (size_t)row * C_ + k0 + sc * 8,
                    lds + dd * 65536 + 32768 + half * 16384 + g * 1024);
        }
    };

    // prologue: tile 0 -> dbuf 0 (8 loads)
    STAGE_A(0, 0, 0); STAGE_A(0, 1, 0); STAGE_B(0, 0, 0); STAGE_B(0, 1, 0);

    const int NT = C_ / 64;   // 16
    short8 af[4], bf_[4];
    for (int t = 0; t < NT; ++t) {
        int d = t & 1, dn = d ^ 1;
        int ts = (t + 1 < NT) ? t + 1 : t;    // tail: dummy re-stage
        const char* Abase = lds + d * 65536 + wm * 16384;
        const char* Bbase = lds + d * 65536 + 32768 + (wn >> 1) * 16384;

#define G1_PH(STG, WN, KS, MH, RDB)                                                  \
        __builtin_amdgcn_s_barrier();                                                \
        STG;                                                                         \
        WAITVM(WN);                                                                  \
        __builtin_amdgcn_s_barrier();                                                \
        __builtin_amdgcn_sched_barrier(0);                                           \
        {                                                                            \
            int kc = (KS) * 4 + q;                                                   \
            _Pragma("unroll")                                                        \
            for (int m = 0; m < 4; ++m) {                                            \
                int lr = ((MH) * 4 + m) * 16 + fr;                                   \
                af[m] = *(const short8*)(Abase + LDSOFF(lr, kc));                    \
            }                                                                        \
            if (RDB) {                                                               \
                _Pragma("unroll")                                                    \
                for (int n = 0; n < 4; ++n) {                                        \
                    int lrb = (wn & 1) * 64 + n * 16 + fr;                           \
                    bf_[n] = *(const short8*)(Bbase + LDSOFF(lrb, kc));              \
                }                                                                    \
            }                                                                        \
            __builtin_amdgcn_s_setprio(1);                                           \
            _Pragma("unroll")                                                        \
            for (int m = 0; m < 4; ++m)                                              \
                _Pragma("unroll")                                                    \
                for (int n = 0; n < 4; ++n)                                          \
                    acc[(MH)*4 + m][n] = __builtin_amdgcn_mfma_f32_16x16x32_bf16(    \
                        af[m], bf_[n], acc[(MH)*4 + m][n], 0, 0, 0);                 \
            __builtin_amdgcn_s_setprio(0);                                           \
        }

        G1_PH(STAGE_A(ts, 0, dn), 2, 0, 0, 1)
        G1_PH(STAGE_A(ts, 1, dn), 4, 0, 1, 0)
        G1_PH(STAGE_B(ts, 0, dn), 6, 1, 0, 1)
        G1_PH(STAGE_B(ts, 1, dn), 8, 1, 1, 0)
    }
    WAITVM(0);

    // epilogue: silu pairing (n even = W1, n odd = W3 of h-group ct*8 + wn*2 + pi)
#pragma unroll
    for (int m = 0; m < 8; ++m)
#pragma unroll
        for (int rg = 0; rg < 4; ++rg) {
            int row = wm * 128 + m * 16 + q * 4 + rg;
            if (rt * 256 + row < ne) {
                size_t gbase = (size_t)(row0 + row) * H_;
#pragma unroll
                for (int pi = 0; pi < 2; ++pi) {
                    float h1 = acc[m][2 * pi][rg];
                    float h3 = acc[m][2 * pi + 1][rg];
                    float g = h1 * h3 / (1.f + __expf(-h1));
                    int h = (ct * 8 + wn * 2 + pi) * 16 + fr;
                    G[gbase + h] = f2bf(g);
                }
            }
        }
}

__global__ __launch_bounds__(512, 2) void gemm2_256(
        const unsigned short* __restrict__ G, const unsigned short* __restrict__ W2t,
        float* __restrict__ out, const int* __restrict__ counts,
        const int* __restrict__ offsets, const int* __restrict__ token_of,
        const float* __restrict__ slotw) {
    int b = blockIdx.x;             // [0, 4096)
    int e = b & 7;                  // expert-pinned XCD swizzle (4x fetch cut, r7)
    int j = b >> 3;                 // [0, 512)
    int ksp = j & 3;
    int ct = (j >> 2) & 3;          // 4 col tiles of 256 over C
    int rt = j >> 4;                // [0, 32) -- full coverage (r10 lesson)
    int ne = counts[e];
    if (rt * 256 >= ne) return;
    int row0 = offsets[e] + rt * 256;
    int n0 = ct * 256;
    int kbase = ksp * (H_ / 4);     // 1024 per split

    extern __shared__ char lds[];

    int tid = threadIdx.x, lane = tid & 63, wid = tid >> 6;
    int wm = wid >> 2, wn = wid & 3;
    int fr = lane & 15, q = lane >> 4;
    int sr = lane & 7, sc = lane >> 3;

    const unsigned short* Ap = G + (size_t)row0 * H_ + kbase;
    const unsigned short* Bp = W2t + ((size_t)e * C_ + n0) * H_ + kbase;

    f32x4 acc[8][4];
#pragma unroll
    for (int m = 0; m < 8; ++m)
#pragma unroll
        for (int n = 0; n < 4; ++n) acc[m][n] = (f32x4){0.f,0.f,0.f,0.f};

    auto STAGE_A = [&](int ts, int half, int dd) {
        int k0 = ts * 64;
#pragma unroll
        for (int j2 = 0; j2 < 2; ++j2) {
            int g = wid * 2 + j2;
            int row = half * 128 + g * 8 + sr;
            gload16(Ap + (size_t)row * H_ + k0 + sc * 8,
                    lds + dd * 65536 + half * 16384 + g * 1024);
        }
    };
    auto STAGE_B = [&](int ts, int half, int dd) {
        int k0 = ts * 64;
#pragma unroll
        for (int j2 = 0; j2 < 2; ++j2) {
            int g = wid * 2 + j2;
            int row = half * 128 + g * 8 + sr;
            gload16(Bp + (size_t)row * H_ + k0 + sc * 8,
                    lds + dd * 65536 + 32768 + half * 16384 + g * 1024);
        }
    };

    STAGE_A(0, 0, 0); STAGE_A(0, 1, 0); STAGE_B(0, 0, 0); STAGE_B(0, 1, 0);

    const int NT = (H_ / 4) / 64;   // 16
    short8 af[4], bf_[4];
    for (int t = 0; t < NT; ++t) {
        int d = t & 1, dn = d ^ 1;
        int ts = (t + 1 < NT) ? t + 1 : t;
        const char* Abase = lds + d * 65536 + wm * 16384;
        const char* Bbase = lds + d * 65536 + 32768 + (wn >> 1) * 16384;

        G1_PH(STAGE_A(ts, 0, dn), 2, 0, 0, 1)
        G1_PH(STAGE_A(ts, 1, dn), 4, 0, 1, 0)
        G1_PH(STAGE_B(ts, 0, dn), 6, 1, 0, 1)
        G1_PH(STAGE_B(ts, 1, dn), 8, 1, 1, 0)
    }
    WAITVM(0);

    // epilogue: scatter-add weighted K-quarter partial into out
#pragma unroll
    for (int m = 0; m < 8; ++m)
#pragma unroll
        for (int rg = 0; rg < 4; ++rg) {
            int row = wm * 128 + m * 16 + q * 4 + rg;
            if (rt * 256 + row < ne) {
                int grow = row0 + row;
                int tok = token_of[grow];
                float w = slotw[grow];
                float* orow = out + (size_t)tok * C_ + n0 + wn * 64;
#pragma unroll
                for (int n = 0; n < 4; ++n)
                    atomicAdd(orow + n * 16 + fr, acc[m][n][rg] * w);
            }
        }
}

// ============ SLOW PATH (fallback if ws too small) ============
#define BM 128
#define BN 128
#define BK 32
__global__ __launch_bounds__(256, 2) void gemm1_slow(
        const unsigned short* __restrict__ Xg, const float* __restrict__ W1,
        const float* __restrict__ W3, unsigned short* __restrict__ G,
        const int* __restrict__ counts, const int* __restrict__ offsets) {
    int ct = blockIdx.x;
    int rslot = blockIdx.y;
    int e = rslot >> 5, rt = rslot & 31;
    int ne = counts[e];
    if (rt * BM >= ne) return;
    int row0 = offsets[e] + rt * BM;
    int n0 = ct * BN;

    __shared__ unsigned short As[BM][LPAD];
    __shared__ unsigned short B1s[BN][LPAD];
    __shared__ unsigned short B3s[BN][LPAD];

    int tid = threadIdx.x;
    int lane = tid & 63, wid = tid >> 6;
    int wr = (wid >> 1) * 64, wc = (wid & 1) * 64;

    f32x4 acc1[4][4], acc3[4][4];
#pragma unroll
    for (int m = 0; m < 4; ++m)
#pragma unroll
        for (int n = 0; n < 4; ++n) {
            acc1[m][n] = (f32x4){0.f,0.f,0.f,0.f};
            acc3[m][n] = (f32x4){0.f,0.f,0.f,0.f};
        }

    const float* B1p = W1 + (size_t)e * C_ * H_ + n0;
    const float* B3p = W3 + (size_t)e * C_ * H_ + n0;
    int chunk = tid & 3, rr = tid >> 2;
    int kq = tid >> 5, n4 = tid & 31;

    for (int k0 = 0; k0 < C_; k0 += BK) {
        __syncthreads();
#pragma unroll
        for (int h = 0; h < 2; ++h) {
            int row = rr + h * 64;
            uint4 v = *(const uint4*)(Xg + (size_t)(row0 + row) * C_ + k0 + chunk * 8);
            *(uint4*)&As[row][chunk * 8] = v;
        }
        {
            float4 r0 = *(const float4*)(B1p + (size_t)(k0 + kq*4 + 0) * H_ + n4*4);
            float4 r1 = *(const float4*)(B1p + (size_t)(k0 + kq*4 + 1) * H_ + n4*4);
            float4 r2 = *(const float4*)(B1p + (size_t)(k0 + kq*4 + 2) * H_ + n4*4);
            float4 r3 = *(const float4*)(B1p + (size_t)(k0 + kq*4 + 3) * H_ + n4*4);
            ushort4 w0 = {f2bf(r0.x), f2bf(r1.x), f2bf(r2.x), f2bf(r3.x)};
            ushort4 w1 = {f2bf(r0.y), f2bf(r1.y), f2bf(r2.y), f2bf(r3.y)};
            ushort4 w2 = {f2bf(r0.z), f2bf(r1.z), f2bf(r2.z), f2bf(r3.z)};
            ushort4 w3 = {f2bf(r0.w), f2bf(r1.w), f2bf(r2.w), f2bf(r3.w)};
            *(ushort4*)&B1s[n4*4+0][kq*4] = w0;
            *(ushort4*)&B1s[n4*4+1][kq*4] = w1;
            *(ushort4*)&B1s[n4*4+2][kq*4] = w2;
            *(ushort4*)&B1s[n4*4+3][kq*4] = w3;
            r0 = *(const float4*)(B3p + (size_t)(k0 + kq*4 + 0) * H_ + n4*4);
            r1 = *(const float4*)(B3p + (size_t)(k0 + kq*4 + 1) * H_ + n4*4);
            r2 = *(const float4*)(B3p + (size_t)(k0 + kq*4 + 2) * H_ + n4*4);
            r3 = *(const float4*)(B3p + (size_t)(k0 + kq*4 + 3) * H_ + n4*4);
            w0 = (ushort4){f2bf(r0.x), f2bf(r1.x), f2bf(r2.x), f2bf(r3.x)};
            w1 = (ushort4){f2bf(r0.y), f2bf(r1.y), f2bf(r2.y), f2bf(r3.y)};
            w2 = (ushort4){f2bf(r0.z), f2bf(r1.z), f2bf(r2.z), f2bf(r3.z)};
            w3 = (ushort4){f2bf(r0.w), f2bf(r1.w), f2bf(r2.w), f2bf(r3.w)};
            *(ushort4*)&B3s[n4*4+0][kq*4] = w0;
            *(ushort4*)&B3s[n4*4+1][kq*4] = w1;
            *(ushort4*)&B3s[n4*4+2][kq*4] = w2;
            *(ushort4*)&B3s[n4*4+3][kq*4] = w3;
        }
        __syncthreads();
        int q = lane >> 4, fr = lane & 15;
        short8 a[4], b1[4], b3[4];
#pragma unroll
        for (int m = 0; m < 4; ++m) a[m] = *(const short8*)&As[wr + m*16 + fr][q*8];
#pragma unroll
        for (int n = 0; n < 4; ++n) {
            b1[n] = *(const short8*)&B1s[wc + n*16 + fr][q*8];
            b3[n] = *(const short8*)&B3s[wc + n*16 + fr][q*8];
        }
#pragma unroll
        for (int m = 0; m < 4; ++m)
#pragma unroll
            for (int n = 0; n < 4; ++n) {
                acc1[m][n] = __builtin_amdgcn_mfma_f32_16x16x32_bf16(a[m], b1[n], acc1[m][n], 0, 0, 0);
                acc3[m][n] = __builtin_amdgcn_mfma_f32_16x16x32_bf16(a[m], b3[n], acc3[m][n], 0, 0, 0);
            }
    }
    int q = lane >> 4, cfr = lane & 15;
#pragma unroll
    for (int m = 0; m < 4; ++m) {
#pragma unroll
        for (int rg = 0; rg < 4; ++rg) {
            int row = wr + m*16 + q*4 + rg;
            if (rt * BM + row < ne) {
                size_t gbase = (size_t)(row0 + row) * H_ + n0;
#pragma unroll
                for (int n = 0; n < 4; ++n) {
                    float h1 = acc1[m][n][rg];
                    float h3 = acc3[m][n][rg];
                    float g = h1 * h3 / (1.f + __expf(-h1));
                    G[gbase + wc + n*16 + cfr] = f2bf(g);
                }
            }
        }
    }
}

__global__ __launch_bounds__(256, 2) void gemm2_slow(
        const unsigned short* __restrict__ G, const float* __restrict__ W2,
        float* __restrict__ out, const int* __restrict__ counts,
        const int* __restrict__ offsets, const int* __restrict__ token_of,
        const float* __restrict__ slotw) {
    int ct = blockIdx.x;
    int rslot = blockIdx.y;
    int e = rslot >> 5, rt = rslot & 31;
    int ne = counts[e];
    if (rt * BM >= ne) return;
    int row0 = offsets[e] + rt * BM;
    int n0 = ct * BN;

    __shared__ unsigned short As[BM][LPAD];
    __shared__ unsigned short Bs[BN][LPAD];

    int tid = threadIdx.x;
    int lane = tid & 63, wid = tid >> 6;
    int wr = (wid >> 1) * 64, wc = (wid & 1) * 64;

    f32x4 acc[4][4];
#pragma unroll
    for (int m = 0; m < 4; ++m)
#pragma unroll
        for (int n = 0; n < 4; ++n) acc[m][n] = (f32x4){0.f,0.f,0.f,0.f};

    const float* Bp = W2 + (size_t)e * H_ * C_ + n0;
    int chunk = tid & 3, rr = tid >> 2;
    int kq = tid >> 5, n4 = tid & 31;

    for (int k0 = 0; k0 < H_; k0 += BK) {
        __syncthreads();
#pragma unroll
        for (int h = 0; h < 2; ++h) {
            int row = rr + h * 64;
            uint4 v = *(const uint4*)(G + (size_t)(row0 + row) * H_ + k0 + chunk * 8);
            *(uint4*)&As[row][chunk * 8] = v;
        }
        {
            float4 r0 = *(const float4*)(Bp + (size_t)(k0 + kq*4 + 0) * C_ + n4*4);
            float4 r1 = *(const float4*)(Bp + (size_t)(k0 + kq*4 + 1) * C_ + n4*4);
            float4 r2 = *(const float4*)(Bp + (size_t)(k0 + kq*4 + 2) * C_ + n4*4);
            float4 r3 = *(const float4*)(Bp + (size_t)(k0 + kq*4 + 3) * C_ + n4*4);
            ushort4 w0 = {f2bf(r0.x), f2bf(r1.x), f2bf(r2.x), f2bf(r3.x)};
            ushort4 w1 = {f2bf(r0.y), f2bf(r1.y), f2bf(r2.y), f2bf(r3.y)};
            ushort4 w2 = {f2bf(r0.z), f2bf(r1.z), f2bf(r2.z), f2bf(r3.z)};
            ushort4 w3 = {f2bf(r0.w), f2bf(r1.w), f2bf(r2.w), f2bf(r3.w)};
            *(ushort4*)&Bs[n4*4+0][kq*4] = w0;
            *(ushort4*)&Bs[n4*4+1][kq*4] = w1;
            *(ushort4*)&Bs[n4*4+2][kq*4] = w2;
            *(ushort4*)&Bs[n4*4+3][kq*4] = w3;
        }
        __syncthreads();
        int q = lane >> 4, fr = lane & 15;
        short8 a[4], b[4];
#pragma unroll
        for (int m = 0; m < 4; ++m) a[m] = *(const short8*)&As[wr + m*16 + fr][q*8];
#pragma unroll
        for (int n = 0; n < 4; ++n) b[n] = *(const short8*)&Bs[wc + n*16 + fr][q*8];
#pragma unroll
        for (int m = 0; m < 4; ++m)
#pragma unroll
            for (int n = 0; n < 4; ++n)
                acc[m][n] = __builtin_amdgcn_mfma_f32_16x16x32_bf16(a[m], b[n], acc[m][n], 0, 0, 0);
    }
    int q = lane >> 4, cfr = lane & 15;
#pragma unroll
    for (int m = 0; m < 4; ++m) {
#pragma unroll
        for (int rg = 0; rg < 4; ++rg) {
            int row = wr + m*16 + q*4 + rg;
            if (rt * BM + row < ne) {
                int grow = row0 + row;
                int tok = token_of[grow];
                float w = slotw[grow];
                float* orow = out + (size_t)tok * C_ + n0;
#pragma unroll
                for (int n = 0; n < 4; ++n)
                    atomicAdd(orow + wc + n*16 + cfr, acc[m][n][rg] * w);
            }
        }
    }
}

extern "C" void kernel_launch(void* const* d_in, const int* in_sizes, int n_in,
                              void* d_out, int out_size, void* d_ws, size_t ws_size,
                              hipStream_t stream) {
    const float* x  = (const float*)d_in[0];
    const float* Wg = (const float*)d_in[1];
    const float* W1 = (const float*)d_in[2];
    const float* W2 = (const float*)d_in[3];
    const float* W3 = (const float*)d_in[4];
    float* out = (float*)d_out;

    char* ws = (char*)d_ws;
    size_t o = 0;
    int*   sel      = (int*)(ws + o);  o += (size_t)NSLOT * 4;
    float* wts      = (float*)(ws + o); o += (size_t)NSLOT * 4;
    int*   pos      = (int*)(ws + o);  o += (size_t)NSLOT * 4;
    int*   token_of = (int*)(ws + o);  o += (size_t)NSLOT * 4;
    float* slotw    = (float*)(ws + o); o += (size_t)NSLOT * 4;
    int*   counts   = (int*)(ws + o);
    int*   offsets  = counts + E_;     o += 256;
    unsigned short* Xg = (unsigned short*)(ws + o); o += (size_t)SPAD * C_ * 2;
    unsigned short* G  = (unsigned short*)(ws + o); o += (size_t)SPAD * H_ * 2;
    size_t need_slow = o;
    unsigned short* W13t = (unsigned short*)(ws + o); o += (size_t)E_ * 8192 * C_ * 2;
    unsigned short* W2t  = W13t;   // W13t region freed after gemm1
    size_t need_fast = o;

    hipMemsetAsync(d_out, 0, (size_t)out_size * sizeof(float), stream);
    if (ws_size < need_slow) return;

    router_kernel<<<N_TOK/4, 256, 0, stream>>>(x, Wg, sel, wts);
    assign_kernel<<<1, 256, 0, stream>>>(sel, wts, counts, offsets, pos, token_of, slotw);
    copy_kernel<<<NSLOT/4, 256, 0, stream>>>(x, pos, Xg);

    if (ws_size >= need_fast) {
        hipFuncSetAttribute((const void*)gemm1_256, hipFuncAttributeMaxDynamicSharedMemorySize, 131072);
        hipFuncSetAttribute((const void*)gemm2_256, hipFuncAttributeMaxDynamicSharedMemorySize, 131072);
        wconv13_kernel<<<dim3(H_/64, C_/64, E_), 256, 0, stream>>>(W1, W13t, 0);
        wconv13_kernel<<<dim3(H_/64, C_/64, E_), 256, 0, stream>>>(W3, W13t, 1);
        gemm1_256<<<dim3(32, 256), 512, 131072, stream>>>(Xg, W13t, G, counts, offsets);
        wconv_kernel<<<dim3(C_/64, H_/64, E_), 256, 0, stream>>>(W2, W2t, H_, C_);
        gemm2_256<<<4096, 512, 131072, stream>>>(G, W2t, out, counts, offsets, token_of, slotw);
    } else {
        gemm1_slow<<<dim3(H_/BN, E_*32), 256, 0, stream>>>(Xg, W1, W3, G, counts, offsets);
        gemm2_slow<<<dim3(C_/BN, E_*32), 256, 0, stream>>>(G, W2, out, counts, offsets, token_of, slotw);
    }
}